// Round 15
// baseline (514.150 us; speedup 1.0000x reference)
//
#include <hip/hip_runtime.h>
#include <hip/hip_bf16.h>
#include <math.h>

typedef unsigned short u16;
typedef __attribute__((ext_vector_type(8))) short bf16x8;
typedef __attribute__((ext_vector_type(4))) float f32x4;
typedef __attribute__((ext_vector_type(16))) float f32x16;
typedef __attribute__((address_space(1))) unsigned int gu32;
typedef __attribute__((address_space(3))) unsigned int lu32;

#define DD 1024
#define PP 32

__device__ __forceinline__ u16 f2bf(float f) {
  unsigned u = __float_as_uint(f);
  unsigned r = u + 0x7fffu + ((u >> 16) & 1u);
  return (u16)(r >> 16);
}
__device__ __forceinline__ float bf2f(u16 h) {
  return __uint_as_float(((unsigned)h) << 16);
}

// tanh-GELU: 0.5 v (1 + tanh(0.7978845608 (v + 0.044715 v^3))); tanh via exp2+rcp.
__device__ __forceinline__ float gelu_t(float v) {
  float u = v + 0.044715f * v * v * v;
  float p = __builtin_amdgcn_exp2f(2.302590614f * u);  // e^{2*0.79788456*u}
  float th = 1.0f - 2.0f * __builtin_amdgcn_rcpf(p + 1.0f);
  return 0.5f * v * (1.0f + th);
}

// ---------------- conversions ----------------
__global__ __launch_bounds__(256) void k_convert(const float* __restrict__ in,
                                                 u16* __restrict__ out, int n4) {
  for (int i = blockIdx.x * 256 + threadIdx.x; i < n4; i += gridDim.x * 256) {
    float4 v = ((const float4*)in)[i];
    ushort4 o;
    o.x = f2bf(v.x); o.y = f2bf(v.y); o.z = f2bf(v.z); o.w = f2bf(v.w);
    ((ushort4*)out)[i] = o;
  }
}

// prototypes [32,1024] f32 -> row-l2-normalized bf16 (for sim)
__global__ __launch_bounds__(256) void k_proto_prep(const float* __restrict__ protos,
                                                    u16* __restrict__ pb) {
  __shared__ float sb[4];
  int row = blockIdx.x, tid = threadIdx.x;
  float4 v = ((const float4*)(protos + row * DD))[tid];
  float q = v.x * v.x + v.y * v.y + v.z * v.z + v.w * v.w;
#pragma unroll
  for (int off = 32; off; off >>= 1) q += __shfl_xor(q, off);
  if ((tid & 63) == 0) sb[tid >> 6] = q;
  __syncthreads();
  q = sb[0] + sb[1] + sb[2] + sb[3];
  float inv = 1.0f / fmaxf(sqrtf(q), 1e-12f);
  ushort4 o;
  o.x = f2bf(v.x * inv); o.y = f2bf(v.y * inv); o.z = f2bf(v.z * inv); o.w = f2bf(v.w * inv);
  ((ushort4*)(pb + row * DD))[tid] = o;
}

// Per row n of Wo: convert Wo[n,0:1024] -> WoB[n,0:1024] bf16 (stride 1088),
// and P2[n,p] = sum_d Wo[n,1024+d]*protos[p,d] (f32) -> WoB[n,1024+p]; zero pad.
__global__ __launch_bounds__(256) void k_p2(const float* __restrict__ Wo,
                                            const float* __restrict__ protos,
                                            u16* __restrict__ WoB) {
  __shared__ float swo[1024];
  int n = blockIdx.x, tid = threadIdx.x;
  // lower half convert
  float4 lv = ((const float4*)(Wo + (size_t)n * 2048))[tid];
  ushort4 lo;
  lo.x = f2bf(lv.x); lo.y = f2bf(lv.y); lo.z = f2bf(lv.z); lo.w = f2bf(lv.w);
  *(ushort4*)(WoB + (size_t)n * 1088 + tid * 4) = lo;
  // upper half -> P2
  ((float4*)swo)[tid] = ((const float4*)(Wo + (size_t)n * 2048 + 1024))[tid];
  __syncthreads();
  int w = tid >> 6, lane = tid & 63;
#pragma unroll
  for (int q = 0; q < 8; ++q) {
    int p = w * 8 + q;
    const float* pr = protos + (size_t)p * 1024 + lane * 16;
    const float* wv = swo + lane * 16;
    float d = 0.f;
#pragma unroll
    for (int j = 0; j < 16; ++j) d += wv[j] * pr[j];
#pragma unroll
    for (int off = 32; off; off >>= 1) d += __shfl_xor(d, off);
    if (lane == 0) WoB[(size_t)n * 1088 + 1024 + p] = f2bf(d);
  }
  if (tid < 32) WoB[(size_t)n * 1088 + 1056 + tid] = 0;
}

// ---------------- 256x256 bf16 GEMM (B^T layout), 32x32x16 MFMA, T2 swizzle ----------------
// C[m,n] = sum_k A'[m,k] * Bm[n,k], A' = [A (lda 1024) | Aext (stride 64, K-tile 16)].
// EPI 1: y = bf16(gelu(acc+bias[n]) + resid) -> u16*, u16-stride 2048 (LDS-transposed stores)
// EPI 2: h stays on-CU; sim partials via 16x16 MFMAs from eb; ||h||^2 partials.
#define GLL(gsrc, ldst) __builtin_amdgcn_global_load_lds((gu32*)(gsrc), (lu32*)(ldst), 16, 0, 0)

template <int EPI, int NT>
__global__ __launch_bounds__(512, 2) void k_gemmF(const u16* __restrict__ A,
                                                  const u16* __restrict__ Aext,
                                                  const u16* __restrict__ Bm, int bstride,
                                                  const float* __restrict__ bias,
                                                  const u16* __restrict__ residb,
                                                  u16* __restrict__ Cout,
                                                  int nbn,
                                                  const u16* __restrict__ pbn,
                                                  float* __restrict__ simp,
                                                  float* __restrict__ ssp) {
  __shared__ u16 Lsh[65536];  // [A dbuf 32768 | B dbuf 32768] u16; reused by epilogue
#define ALS(bufv, idx) (Lsh + (bufv) * 16384 + (idx))
#define BLS(bufv, idx) (Lsh + 32768 + (bufv) * 16384 + (idx))
  const int tid = threadIdx.x;
  const int wid = tid >> 6, lane = tid & 63;
  const int wm = wid >> 2, wn = wid & 3;
  const int lm = lane & 15, lk = lane >> 4;
  const int l31 = lane & 31, l5 = lane >> 5;

  const int scol_sw = (((lane & 7) ^ ((lane >> 3) & 7)) << 3);
  const int srow = lane >> 3;

  // XCD chunked swizzle (nwg % 8 == 0)
  int g = blockIdx.x;
  int cpx = gridDim.x >> 3;
  int lin = (g & 7) * cpx + (g >> 3);
  int bn = lin % nbn, bm = lin / nbn;
  const size_t bmBase = (size_t)bm * 256;
  const size_t bnBase = (size_t)bn * 256;

  f32x16 acc[4][2];  // [fm row-group of 32][fn col-group of 32]
#pragma unroll
  for (int i = 0; i < 4; ++i)
#pragma unroll
    for (int j = 0; j < 2; ++j)
#pragma unroll
      for (int q = 0; q < 16; ++q) acc[i][j][q] = 0.f;

  bf16x8 a[4][2], b[2][2];

#define STAGE_A(bufv, kt, mh) do {                                              \
    int arow = (mh) * 64 + wid * 8 + srow;                                      \
    const u16 *ap0, *ap1;                                                       \
    if ((kt) < 16) {                                                            \
      ap0 = A + (bmBase + arow) * (size_t)1024 + scol_sw + (kt) * 64;           \
      ap1 = A + (bmBase + 128 + arow) * (size_t)1024 + scol_sw + (kt) * 64;     \
    } else {                                                                    \
      ap0 = Aext + (bmBase + arow) * (size_t)64 + scol_sw;                      \
      ap1 = Aext + (bmBase + 128 + arow) * (size_t)64 + scol_sw;                \
    }                                                                           \
    GLL(ap0, ALS(bufv, ((mh) * 64 + wid * 8) * 64));                            \
    GLL(ap1, ALS(bufv, (128 + (mh) * 64 + wid * 8) * 64));                      \
  } while (0)

#define STAGE_B(bufv, kt, nh) do {                                              \
    int br0 = ((wid >> 2) << 6) + (nh) * 32 + ((wid & 3) << 3);                 \
    int bcol = scol_sw + (kt) * 64;                                             \
    GLL(Bm + (bnBase + br0 + srow) * (size_t)bstride + bcol, BLS(bufv, br0 * 64)); \
    GLL(Bm + (bnBase + 128 + br0 + srow) * (size_t)bstride + bcol, BLS(bufv, (128 + br0) * 64)); \
  } while (0)

#define BARRIER do { __builtin_amdgcn_s_barrier(); asm volatile("" ::: "memory"); } while (0)

  // one k-half: k-slices {kh*2, kh*2+1} of 16; 12 ds_read_b128 + 16 MFMA(32x32x16)
#define KHALF(P, kh) do {                                                       \
    _Pragma("unroll") for (int fm = 0; fm < 4; ++fm) {                          \
      int row = wm * 128 + fm * 32 + l31;                                       \
      _Pragma("unroll") for (int ks = 0; ks < 2; ++ks)                          \
        a[fm][ks] = *(const bf16x8*)ALS(P, row * 64 +                           \
            ((((kh) * 2 + ks) * 16 + l5 * 8) ^ ((l31 & 7) << 3)));              \
    }                                                                           \
    _Pragma("unroll") for (int fn = 0; fn < 2; ++fn) {                          \
      int row = wn * 64 + fn * 32 + l31;                                        \
      _Pragma("unroll") for (int ks = 0; ks < 2; ++ks)                          \
        b[fn][ks] = *(const bf16x8*)BLS(P, row * 64 +                           \
            ((((kh) * 2 + ks) * 16 + l5 * 8) ^ ((l31 & 7) << 3)));              \
    }                                                                           \
    __builtin_amdgcn_s_setprio(1);                                              \
    _Pragma("unroll") for (int fm = 0; fm < 4; ++fm)                            \
    _Pragma("unroll") for (int fn = 0; fn < 2; ++fn) {                          \
      acc[fm][fn] = __builtin_amdgcn_mfma_f32_32x32x16_bf16(                    \
          a[fm][0], b[fn][0], acc[fm][fn], 0, 0, 0);                            \
      acc[fm][fn] = __builtin_amdgcn_mfma_f32_32x32x16_bf16(                    \
          a[fm][1], b[fn][1], acc[fm][fn], 0, 0, 0);                            \
    }                                                                           \
    __builtin_amdgcn_s_setprio(0);                                              \
  } while (0)

#define TILE(T, P) do {                                                         \
    asm volatile("s_waitcnt vmcnt(0)" ::: "memory");                            \
    BARRIER;                                                                    \
    if ((T) + 1 < NT) {                                                         \
      STAGE_A((P) ^ 1, (T) + 1, 0); STAGE_B((P) ^ 1, (T) + 1, 0);               \
      STAGE_A((P) ^ 1, (T) + 1, 1); STAGE_B((P) ^ 1, (T) + 1, 1);               \
    }                                                                           \
    KHALF(P, 0);                                                                \
    KHALF(P, 1);                                                                \
  } while (0)

  // prologue: stage tile0 into buf0
  STAGE_A(0, 0, 0); STAGE_B(0, 0, 0); STAGE_A(0, 0, 1); STAGE_B(0, 0, 1);

#pragma unroll
  for (int T = 0; T + 1 < NT; T += 2) {
    TILE(T, 0);
    TILE(T + 1, 1);
  }
  if (NT & 1) TILE(NT - 1, 0);  // odd NT tail (parity: NT-1 even)

  // ---- epilogue ----
  __syncthreads();  // all waves done reading the K-loop tiles
  u16* eb = Lsh + wid * 4608;  // per-wave 64 x 72 u16 (16B-aligned rows)
  const size_t gr0 = bmBase + wm * 128;
  const int gc0 = (int)bnBase + wn * 64;
  float bv[2];
  bv[0] = bias[gc0 + l31];
  bv[1] = bias[gc0 + 32 + l31];

  if (EPI == 2) {
    // sim/norm fused epilogue: h stays on-CU
    bf16x8 bp[2][2];
#pragma unroll
    for (int ph = 0; ph < 2; ++ph)
#pragma unroll
      for (int kk = 0; kk < 2; ++kk)
        bp[ph][kk] = *(const bf16x8*)(pbn + (size_t)(ph * 16 + lm) * 1024 + gc0 + kk * 32 + lk * 8);
    f32x4 sa[2][4][2];
#pragma unroll
    for (int ch = 0; ch < 2; ++ch) {
      // scatter h = acc + bias (bf16) into eb; 32x32 C/D: col=l31, row=(q&3)+8(q>>2)+4*l5
#pragma unroll
      for (int fm2 = 0; fm2 < 2; ++fm2) {
#pragma unroll
        for (int fn = 0; fn < 2; ++fn) {
#pragma unroll
          for (int q = 0; q < 16; ++q) {
            int rowL = fm2 * 32 + (q & 3) + ((q >> 2) << 3) + (l5 << 2);
            int col = fn * 32 + l31;
            eb[rowL * 72 + (col ^ (((rowL >> 2) & 3) << 3))] =
                f2bf(acc[ch * 2 + fm2][fn][q] + bv[fn]);
          }
        }
      }
      // A-frags from eb (row=lm, k=lk*8+j), ||h||^2 partial, sim MFMAs (16x16)
#pragma unroll
      for (int rg = 0; rg < 4; ++rg) {
        int rowL = rg * 16 + lm;
        int swz = ((lm >> 2) & 3) << 3;
        bf16x8 af0 = *(const bf16x8*)&eb[rowL * 72 + ((lk * 8) ^ swz)];
        bf16x8 af1 = *(const bf16x8*)&eb[rowL * 72 + ((32 + lk * 8) ^ swz)];
        float sq = 0.f;
#pragma unroll
        for (int j = 0; j < 8; ++j) {
          float h0 = bf2f((u16)af0[j]), h1 = bf2f((u16)af1[j]);
          sq += h0 * h0 + h1 * h1;
        }
        sq += __shfl_xor(sq, 16);
        sq += __shfl_xor(sq, 32);
        if (lk == 0)
          ssp[(gr0 + ch * 64 + rg * 16 + lm) * 16 + bn * 4 + wn] = sq;
        f32x4 z = {0.f, 0.f, 0.f, 0.f};
        f32x4 s0 = __builtin_amdgcn_mfma_f32_16x16x32_bf16(af0, bp[0][0], z, 0, 0, 0);
        s0 = __builtin_amdgcn_mfma_f32_16x16x32_bf16(af1, bp[0][1], s0, 0, 0, 0);
        f32x4 s1 = __builtin_amdgcn_mfma_f32_16x16x32_bf16(af0, bp[1][0], z, 0, 0, 0);
        s1 = __builtin_amdgcn_mfma_f32_16x16x32_bf16(af1, bp[1][1], s1, 0, 0, 0);
        sa[ch][rg][0] = s0;
        sa[ch][rg][1] = s1;
      }
    }
    __syncthreads();            // all waves done reading their eb
    float* part = (float*)Lsh;  // [4 wn][256 rows][32 p] f32 = 128 KB exactly
#pragma unroll
    for (int ch = 0; ch < 2; ++ch)
#pragma unroll
      for (int rg = 0; rg < 4; ++rg)
#pragma unroll
        for (int ph = 0; ph < 2; ++ph)
#pragma unroll
          for (int r = 0; r < 4; ++r) {
            int row = wm * 128 + ch * 64 + rg * 16 + lk * 4 + r;
            part[wn * 8192 + row * 32 + ph * 16 + lm] = sa[ch][rg][ph][r];
          }
    __syncthreads();
    // wn-reduce + coalesced global write of sim partials (per bn)
    for (int i = tid; i < 8192; i += 512) {
      int row = i >> 5, p = i & 31;
      float s = part[row * 32 + p] + part[8192 + row * 32 + p] +
                part[16384 + row * 32 + p] + part[24576 + row * 32 + p];
      simp[(bmBase + row) * 128 + (size_t)bn * 32 + p] = s;
    }
  } else {
    // EPI == 1: gelu + resid, LDS transpose -> coalesced 16B stores
#pragma unroll
    for (int ch = 0; ch < 2; ++ch) {
#pragma unroll
      for (int fm2 = 0; fm2 < 2; ++fm2) {
#pragma unroll
        for (int fn = 0; fn < 2; ++fn) {
#pragma unroll
          for (int q = 0; q < 16; ++q) {
            int rowL = fm2 * 32 + (q & 3) + ((q >> 2) << 3) + (l5 << 2);
            int col = fn * 32 + l31;
            float v = gelu_t(acc[ch * 2 + fm2][fn][q] + bv[fn]);
            eb[rowL * 72 + (col ^ (((rowL >> 2) & 3) << 3))] = f2bf(v);
          }
        }
      }
#pragma unroll
      for (int i = 0; i < 8; ++i) {
        int rowL = i * 8 + (lane >> 3);
        int c8 = (lane & 7) * 8;
        bf16x8 yv = *(const bf16x8*)&eb[rowL * 72 + (c8 ^ (((rowL >> 2) & 3) << 3))];
        size_t grow = gr0 + ch * 64 + rowL;
        bf16x8 rv = *(const bf16x8*)(residb + grow * 1024 + gc0 + c8);
        bf16x8 ov;
#pragma unroll
        for (int j = 0; j < 8; ++j)
          ov[j] = (short)f2bf(bf2f((u16)yv[j]) + bf2f((u16)rv[j]));
        *(bf16x8*)(Cout + grow * 2048 + gc0 + c8) = ov;
      }
    }
  }
#undef STAGE_A
#undef STAGE_B
#undef KHALF
#undef TILE
#undef BARRIER
#undef ALS
#undef BLS
}

// ---------------- softmax over the 4 bn sim-partials -> ab [B,64] bf16 ----------------
__global__ __launch_bounds__(256) void k_soft(const float* __restrict__ simp,
                                              const float* __restrict__ ssp,
                                              u16* __restrict__ ab) {
  const int wv = threadIdx.x >> 6, lane = threadIdx.x & 63;
  int rowBase = blockIdx.x * 32 + wv * 8;
#pragma unroll
  for (int i = 0; i < 8; ++i) {
    int row = rowBase + i;
    const float* sp = simp + (size_t)row * 128;
    float v = sp[lane] + sp[64 + lane];
    v += __shfl_xor(v, 32);  // every lane: sim[lane & 31] (full over 4 bn)
    float ssv = (lane < 16) ? ssp[(size_t)row * 16 + lane] : 0.f;
    ssv += __shfl_xor(ssv, 1); ssv += __shfl_xor(ssv, 2);
    ssv += __shfl_xor(ssv, 4); ssv += __shfl_xor(ssv, 8);
    float ss = __shfl(ssv, 0);
    float inv = 10.0f / fmaxf(sqrtf(ss), 1e-12f);
    float s = v * inv;
    float m = s;
#pragma unroll
    for (int off = 1; off < 32; off <<= 1) m = fmaxf(m, __shfl_xor(m, off));
    float e = expf(s - m);
    float sum = e;
#pragma unroll
    for (int off = 1; off < 32; off <<= 1) sum += __shfl_xor(sum, off);
    float a = e / sum;
    ab[(size_t)row * 64 + lane] = (lane < 32) ? f2bf(a) : (u16)0;
  }
}

// ---------------- LayerNorm: read y bf16 (low half of each out-row slot), write f32 ----
__global__ __launch_bounds__(256) void k_ln2(u16* __restrict__ ybase,
                                             float* __restrict__ out,
                                             const float* __restrict__ gamma,
                                             const float* __restrict__ beta) {
  __shared__ float sb[8];
  size_t row = blockIdx.x;
  int tid = threadIdx.x;
  ushort4 v4 = ((const ushort4*)(ybase + row * 2048))[tid];
  float y0 = bf2f(v4.x), y1 = bf2f(v4.y), y2 = bf2f(v4.z), y3 = bf2f(v4.w);
  float s = y0 + y1 + y2 + y3;
  float q = y0 * y0 + y1 * y1 + y2 * y2 + y3 * y3;
#pragma unroll
  for (int off = 32; off; off >>= 1) { s += __shfl_xor(s, off); q += __shfl_xor(q, off); }
  if ((tid & 63) == 0) { sb[tid >> 6] = s; sb[4 + (tid >> 6)] = q; }
  __syncthreads();  // also drains all loads before any store below
  s = sb[0] + sb[1] + sb[2] + sb[3];
  q = sb[4] + sb[5] + sb[6] + sb[7];
  float mu = s * (1.f / 1024.f);
  float var = q * (1.f / 1024.f) - mu * mu;
  float rstd = rsqrtf(var + 1e-5f);
  float4 g = ((const float4*)gamma)[tid];
  float4 b = ((const float4*)beta)[tid];
  float4 o;
  o.x = (y0 - mu) * rstd * g.x + b.x;
  o.y = (y1 - mu) * rstd * g.y + b.y;
  o.z = (y2 - mu) * rstd * g.z + b.z;
  o.w = (y3 - mu) * rstd * g.w + b.w;
  ((float4*)(out + (row << 10)))[tid] = o;
}

extern "C" void kernel_launch(void* const* d_in, const int* in_sizes, int n_in,
                              void* d_out, int out_size, void* d_ws, size_t ws_size,
                              hipStream_t stream) {
  const float* x      = (const float*)d_in[0];
  const float* Wi     = (const float*)d_in[1];
  const float* bi     = (const float*)d_in[2];
  const float* Wo     = (const float*)d_in[3];
  const float* bo     = (const float*)d_in[4];
  const float* gamma  = (const float*)d_in[5];
  const float* beta   = (const float*)d_in[6];
  const float* protos = (const float*)d_in[7];
  const int Brows = in_sizes[0] / DD;  // 65536

  u16* xb   = (u16*)d_ws;                        // [B, 1024] bf16
  u16* WiB  = xb + (size_t)Brows * 1024;         // [1024, 1024]
  u16* WoB  = WiB + (size_t)1024 * 1024;         // [1024, 1088]  (Wo1 | P2 | pad)
  u16* pb   = WoB + (size_t)1024 * 1088;         // [32, 1024] normalized
  u16* ab   = pb + (size_t)PP * DD;              // [B, 64] attn (cols 32..63 zero)
  float* simp = (float*)(ab + (size_t)Brows * 64);   // [B, 4, 32] sim partials (per bn)
  float* ssp  = simp + (size_t)Brows * 128;          // [B, 16] ||h||^2 partials (bn*4+wn)
  u16* ybuf = (u16*)d_out;                       // y bf16, u16-stride 2048 (low half of slots)

  k_convert<<<4096, 256, 0, stream>>>(x, xb, Brows * 256);
  k_convert<<<1024, 256, 0, stream>>>(Wi, WiB, 1024 * 1024 / 4);
  k_proto_prep<<<PP, 256, 0, stream>>>(protos, pb);
  k_p2<<<1024, 256, 0, stream>>>(Wo, protos, WoB);

  const int nbn = 1024 / 256;                    // 4 col-blocks
  const int nwg = nbn * (Brows / 256);           // 1024 blocks (mod 8 == 0)

  // h = x @ Wi^T + bi fused with sim/norm partials (h never hits HBM)
  k_gemmF<2, 16><<<nwg, 512, 0, stream>>>(xb, xb, WiB, 1024, bi, nullptr,
                                          nullptr, nbn, pb, simp, ssp);
  // softmax over partials -> attn
  k_soft<<<Brows / 32, 256, 0, stream>>>(simp, ssp, ab);
  // y = bf16(gelu(x @ Wo1^T + attn @ P2 + bo) + bf16(x))  (K = 1088, 17 tiles)
  k_gemmF<1, 17><<<nwg, 512, 0, stream>>>(xb, ab, WoB, 1088, bo, xb,
                                          ybuf, nbn, nullptr, nullptr, nullptr);
  // LayerNorm: y bf16 -> out f32 (in-slot)
  k_ln2<<<Brows, 256, 0, stream>>>(ybuf, (float*)d_out, gamma, beta);
}

// Round 16
// 490.991 us; speedup vs baseline: 1.0472x; 1.0472x over previous
//
#include <hip/hip_runtime.h>
#include <hip/hip_bf16.h>
#include <math.h>

typedef unsigned short u16;
typedef __attribute__((ext_vector_type(8))) short bf16x8;
typedef __attribute__((ext_vector_type(4))) float f32x4;
typedef __attribute__((address_space(1))) unsigned int gu32;
typedef __attribute__((address_space(3))) unsigned int lu32;

#define DD 1024
#define PP 32

__device__ __forceinline__ u16 f2bf(float f) {
  unsigned u = __float_as_uint(f);
  unsigned r = u + 0x7fffu + ((u >> 16) & 1u);
  return (u16)(r >> 16);
}
__device__ __forceinline__ float bf2f(u16 h) {
  return __uint_as_float(((unsigned)h) << 16);
}

// tanh-GELU: 0.5 v (1 + tanh(0.7978845608 (v + 0.044715 v^3))); tanh via exp2+rcp.
__device__ __forceinline__ float gelu_t(float v) {
  float u = v + 0.044715f * v * v * v;
  float p = __builtin_amdgcn_exp2f(2.302590614f * u);  // e^{2*0.79788456*u}
  float th = 1.0f - 2.0f * __builtin_amdgcn_rcpf(p + 1.0f);
  return 0.5f * v * (1.0f + th);
}

// ---------------- conversions ----------------
__global__ __launch_bounds__(256) void k_convert(const float* __restrict__ in,
                                                 u16* __restrict__ out, int n4) {
  for (int i = blockIdx.x * 256 + threadIdx.x; i < n4; i += gridDim.x * 256) {
    float4 v = ((const float4*)in)[i];
    ushort4 o;
    o.x = f2bf(v.x); o.y = f2bf(v.y); o.z = f2bf(v.z); o.w = f2bf(v.w);
    ((ushort4*)out)[i] = o;
  }
}

// prototypes [32,1024] f32 -> row-l2-normalized bf16 (for sim)
__global__ __launch_bounds__(256) void k_proto_prep(const float* __restrict__ protos,
                                                    u16* __restrict__ pb) {
  __shared__ float sb[4];
  int row = blockIdx.x, tid = threadIdx.x;
  float4 v = ((const float4*)(protos + row * DD))[tid];
  float q = v.x * v.x + v.y * v.y + v.z * v.z + v.w * v.w;
#pragma unroll
  for (int off = 32; off; off >>= 1) q += __shfl_xor(q, off);
  if ((tid & 63) == 0) sb[tid >> 6] = q;
  __syncthreads();
  q = sb[0] + sb[1] + sb[2] + sb[3];
  float inv = 1.0f / fmaxf(sqrtf(q), 1e-12f);
  ushort4 o;
  o.x = f2bf(v.x * inv); o.y = f2bf(v.y * inv); o.z = f2bf(v.z * inv); o.w = f2bf(v.w * inv);
  ((ushort4*)(pb + row * DD))[tid] = o;
}

// Per row n of Wo: convert Wo[n,0:1024] -> WoB[n,0:1024] bf16 (stride 1088),
// and P2[n,p] = sum_d Wo[n,1024+d]*protos[p,d] (f32) -> WoB[n,1024+p]; zero pad.
__global__ __launch_bounds__(256) void k_p2(const float* __restrict__ Wo,
                                            const float* __restrict__ protos,
                                            u16* __restrict__ WoB) {
  __shared__ float swo[1024];
  int n = blockIdx.x, tid = threadIdx.x;
  // lower half convert
  float4 lv = ((const float4*)(Wo + (size_t)n * 2048))[tid];
  ushort4 lo;
  lo.x = f2bf(lv.x); lo.y = f2bf(lv.y); lo.z = f2bf(lv.z); lo.w = f2bf(lv.w);
  *(ushort4*)(WoB + (size_t)n * 1088 + tid * 4) = lo;
  // upper half -> P2
  ((float4*)swo)[tid] = ((const float4*)(Wo + (size_t)n * 2048 + 1024))[tid];
  __syncthreads();
  int w = tid >> 6, lane = tid & 63;
#pragma unroll
  for (int q = 0; q < 8; ++q) {
    int p = w * 8 + q;
    const float* pr = protos + (size_t)p * 1024 + lane * 16;
    const float* wv = swo + lane * 16;
    float d = 0.f;
#pragma unroll
    for (int j = 0; j < 16; ++j) d += wv[j] * pr[j];
#pragma unroll
    for (int off = 32; off; off >>= 1) d += __shfl_xor(d, off);
    if (lane == 0) WoB[(size_t)n * 1088 + 1024 + p] = f2bf(d);
  }
  if (tid < 32) WoB[(size_t)n * 1088 + 1056 + tid] = 0;
}

// ---------------- 256x256 bf16 GEMM (B^T layout), T2 swizzle, merged sync ----------------
// C[m,n] = sum_k A'[m,k] * Bm[n,k], A' = [A (lda 1024) | Aext (stride 64, K-tile 16)].
// EPI 1: C = bf16(gelu(acc+bias[n]) + bf2f(residb[m*1024+n])) -> u16*, u16-stride 2048
//        (y bf16 packed into the low half of each f32 out-row slot); LDS-transposed stores.
// EPI 2: h = acc + bias never leaves the CU: per-wave eb holds the h chunk; compute
//        ||h||^2 partials -> ssp[B][16] (bn*4+wn) and sim partials = h @ pn^T via 32
//        extra MFMAs; wn-reduce through LDS -> simp[B][4][32] (bn).
#define GLL(gsrc, ldst) __builtin_amdgcn_global_load_lds((gu32*)(gsrc), (lu32*)(ldst), 16, 0, 0)

template <int EPI, int NT>
__global__ __launch_bounds__(512, 2) void k_gemmF(const u16* __restrict__ A,
                                                  const u16* __restrict__ Aext,
                                                  const u16* __restrict__ Bm, int bstride,
                                                  const float* __restrict__ bias,
                                                  const u16* __restrict__ residb,
                                                  u16* __restrict__ Cout,
                                                  int nbn,
                                                  const u16* __restrict__ pbn,
                                                  float* __restrict__ simp,
                                                  float* __restrict__ ssp) {
  __shared__ u16 Lsh[65536];  // [A dbuf 32768 | B dbuf 32768] u16; reused by epilogue
#define ALS(bufv, idx) (Lsh + (bufv) * 16384 + (idx))
#define BLS(bufv, idx) (Lsh + 32768 + (bufv) * 16384 + (idx))
  const int tid = threadIdx.x;
  const int wid = tid >> 6, lane = tid & 63;
  const int wm = wid >> 2, wn = wid & 3;
  const int lm = lane & 15, lk = lane >> 4;

  const int scol_sw = (((lane & 7) ^ ((lane >> 3) & 7)) << 3);
  const int srow = lane >> 3;

  // XCD chunked swizzle (nwg % 8 == 0)
  int g = blockIdx.x;
  int cpx = gridDim.x >> 3;
  int lin = (g & 7) * cpx + (g >> 3);
  int bn = lin % nbn, bm = lin / nbn;
  const size_t bmBase = (size_t)bm * 256;
  const size_t bnBase = (size_t)bn * 256;

  f32x4 acc[8][4];
#pragma unroll
  for (int i = 0; i < 8; ++i)
#pragma unroll
    for (int j = 0; j < 4; ++j) acc[i][j] = (f32x4){0.f, 0.f, 0.f, 0.f};

  bf16x8 a[4][2], b0[2][2], b1[2][2];

#define STAGE_A(bufv, kt, mh) do {                                              \
    int arow = (mh) * 64 + wid * 8 + srow;                                      \
    const u16 *ap0, *ap1;                                                       \
    if ((kt) < 16) {                                                            \
      ap0 = A + (bmBase + arow) * (size_t)1024 + scol_sw + (kt) * 64;           \
      ap1 = A + (bmBase + 128 + arow) * (size_t)1024 + scol_sw + (kt) * 64;     \
    } else {                                                                    \
      ap0 = Aext + (bmBase + arow) * (size_t)64 + scol_sw;                      \
      ap1 = Aext + (bmBase + 128 + arow) * (size_t)64 + scol_sw;                \
    }                                                                           \
    GLL(ap0, ALS(bufv, ((mh) * 64 + wid * 8) * 64));                            \
    GLL(ap1, ALS(bufv, (128 + (mh) * 64 + wid * 8) * 64));                      \
  } while (0)

#define STAGE_B(bufv, kt, nh) do {                                              \
    int br0 = ((wid >> 2) << 6) + (nh) * 32 + ((wid & 3) << 3);                 \
    int bcol = scol_sw + (kt) * 64;                                             \
    GLL(Bm + (bnBase + br0 + srow) * (size_t)bstride + bcol, BLS(bufv, br0 * 64)); \
    GLL(Bm + (bnBase + 128 + br0 + srow) * (size_t)bstride + bcol, BLS(bufv, (128 + br0) * 64)); \
  } while (0)

#define LOAD_A(bufv, mh) do {                                                   \
    _Pragma("unroll") for (int mi2 = 0; mi2 < 4; ++mi2) {                       \
      int row = wm * 128 + (mh) * 64 + mi2 * 16 + lm;                           \
      _Pragma("unroll") for (int kk = 0; kk < 2; ++kk)                          \
        a[mi2][kk] = *(const bf16x8*)ALS(bufv, row * 64 + ((kk * 32 + lk * 8) ^ ((lm & 7) << 3))); \
    }                                                                           \
  } while (0)

#define LOAD_B(dst, bufv, nh) do {                                              \
    _Pragma("unroll") for (int ni2 = 0; ni2 < 2; ++ni2) {                       \
      int row = wn * 64 + (nh) * 32 + ni2 * 16 + lm;                            \
      _Pragma("unroll") for (int kk = 0; kk < 2; ++kk)                          \
        dst[ni2][kk] = *(const bf16x8*)BLS(bufv, row * 64 + ((kk * 32 + lk * 8) ^ ((lm & 7) << 3))); \
    }                                                                           \
  } while (0)

#define BARRIER do { __builtin_amdgcn_s_barrier(); asm volatile("" ::: "memory"); } while (0)

#define MFMA_Q(bb, mh, nh) do {                                                 \
    __builtin_amdgcn_s_setprio(1);                                              \
    _Pragma("unroll") for (int mi2 = 0; mi2 < 4; ++mi2)                         \
    _Pragma("unroll") for (int ni2 = 0; ni2 < 2; ++ni2)                         \
    _Pragma("unroll") for (int kk = 0; kk < 2; ++kk)                            \
      acc[(mh) * 4 + mi2][(nh) * 2 + ni2] = __builtin_amdgcn_mfma_f32_16x16x32_bf16( \
          a[mi2][kk], bb[ni2][kk], acc[(mh) * 4 + mi2][(nh) * 2 + ni2], 0, 0, 0); \
    __builtin_amdgcn_s_setprio(0);                                              \
  } while (0)

#define TILE(T, P) do {                                                         \
    asm volatile("s_waitcnt vmcnt(0)" ::: "memory");                            \
    BARRIER;                                                                    \
    if ((T) + 1 < NT) {                                                         \
      STAGE_A((P) ^ 1, (T) + 1, 0); STAGE_B((P) ^ 1, (T) + 1, 0);               \
      STAGE_A((P) ^ 1, (T) + 1, 1); STAGE_B((P) ^ 1, (T) + 1, 1);               \
    }                                                                           \
    LOAD_A(P, 0); LOAD_B(b0, P, 0);                                             \
    MFMA_Q(b0, 0, 0);                                                           \
    LOAD_B(b1, P, 1);                                                           \
    MFMA_Q(b1, 0, 1);                                                           \
    LOAD_A(P, 1);                                                               \
    MFMA_Q(b1, 1, 1);                                                           \
    MFMA_Q(b0, 1, 0);                                                           \
  } while (0)

  // prologue: stage tile0 into buf0
  STAGE_A(0, 0, 0); STAGE_B(0, 0, 0); STAGE_A(0, 0, 1); STAGE_B(0, 0, 1);

#pragma unroll
  for (int T = 0; T + 1 < NT; T += 2) {
    TILE(T, 0);
    TILE(T + 1, 1);
  }
  if (NT & 1) TILE(NT - 1, 0);  // odd NT tail (parity: NT-1 even)

  // ---- epilogue ----
  __syncthreads();  // all waves done reading the K-loop tiles
  u16* eb = Lsh + wid * 4608;  // per-wave 64 x 72 u16 (16B-aligned rows)
  const size_t gr0 = bmBase + wm * 128;
  const int gc0 = (int)bnBase + wn * 64;

  if (EPI == 2) {
    // sim/norm fused epilogue: h stays on-CU
    bf16x8 bp[2][2];
#pragma unroll
    for (int ph = 0; ph < 2; ++ph)
#pragma unroll
      for (int kk = 0; kk < 2; ++kk)
        bp[ph][kk] = *(const bf16x8*)(pbn + (size_t)(ph * 16 + lm) * 1024 + gc0 + kk * 32 + lk * 8);
    f32x4 sa[2][4][2];
#pragma unroll
    for (int ch = 0; ch < 2; ++ch) {
      // scatter h = acc + bias (bf16) into eb (swizzled)
#pragma unroll
      for (int mi2 = 0; mi2 < 4; ++mi2) {
        int mi = ch * 4 + mi2;
#pragma unroll
        for (int ni = 0; ni < 4; ++ni) {
          int col = ni * 16 + lm;
          float bv = bias[gc0 + ni * 16 + lm];
#pragma unroll
          for (int r = 0; r < 4; ++r) {
            int rowL = mi2 * 16 + lk * 4 + r;
            eb[rowL * 72 + (col ^ (((rowL >> 2) & 3) << 3))] = f2bf(acc[mi][ni][r] + bv);
          }
        }
      }
      // A-frags from eb (row=lm, k=lk*8+j), ||h||^2 partial, sim MFMAs
#pragma unroll
      for (int rg = 0; rg < 4; ++rg) {
        int rowL = rg * 16 + lm;
        int swz = ((lm >> 2) & 3) << 3;
        bf16x8 af0 = *(const bf16x8*)&eb[rowL * 72 + ((lk * 8) ^ swz)];
        bf16x8 af1 = *(const bf16x8*)&eb[rowL * 72 + ((32 + lk * 8) ^ swz)];
        float sq = 0.f;
#pragma unroll
        for (int j = 0; j < 8; ++j) {
          float h0 = bf2f((u16)af0[j]), h1 = bf2f((u16)af1[j]);
          sq += h0 * h0 + h1 * h1;
        }
        sq += __shfl_xor(sq, 16);
        sq += __shfl_xor(sq, 32);
        if (lk == 0)
          ssp[(gr0 + ch * 64 + rg * 16 + lm) * 16 + bn * 4 + wn] = sq;
        f32x4 z = {0.f, 0.f, 0.f, 0.f};
        f32x4 s0 = __builtin_amdgcn_mfma_f32_16x16x32_bf16(af0, bp[0][0], z, 0, 0, 0);
        s0 = __builtin_amdgcn_mfma_f32_16x16x32_bf16(af1, bp[0][1], s0, 0, 0, 0);
        f32x4 s1 = __builtin_amdgcn_mfma_f32_16x16x32_bf16(af0, bp[1][0], z, 0, 0, 0);
        s1 = __builtin_amdgcn_mfma_f32_16x16x32_bf16(af1, bp[1][1], s1, 0, 0, 0);
        sa[ch][rg][0] = s0;
        sa[ch][rg][1] = s1;
      }
    }
    __syncthreads();            // all waves done reading their eb
    float* part = (float*)Lsh;  // [4 wn][256 rows][32 p] f32 = 128 KB exactly
#pragma unroll
    for (int ch = 0; ch < 2; ++ch)
#pragma unroll
      for (int rg = 0; rg < 4; ++rg)
#pragma unroll
        for (int ph = 0; ph < 2; ++ph)
#pragma unroll
          for (int r = 0; r < 4; ++r) {
            int row = wm * 128 + ch * 64 + rg * 16 + lk * 4 + r;
            part[wn * 8192 + row * 32 + ph * 16 + lm] = sa[ch][rg][ph][r];
          }
    __syncthreads();
    // wn-reduce + coalesced global write of sim partials (per bn)
    for (int i = tid; i < 8192; i += 512) {
      int row = i >> 5, p = i & 31;
      float s = part[row * 32 + p] + part[8192 + row * 32 + p] +
                part[16384 + row * 32 + p] + part[24576 + row * 32 + p];
      simp[(bmBase + row) * 128 + (size_t)bn * 32 + p] = s;
    }
  } else {
    // EPI == 1: gelu + resid, LDS transpose -> coalesced 16B stores
#pragma unroll
    for (int ch = 0; ch < 2; ++ch) {
#pragma unroll
      for (int mi2 = 0; mi2 < 4; ++mi2) {
        int mi = ch * 4 + mi2;
#pragma unroll
        for (int ni = 0; ni < 4; ++ni) {
          int col = ni * 16 + lm;
          float bv = bias[gc0 + ni * 16 + lm];
#pragma unroll
          for (int r = 0; r < 4; ++r) {
            int rowL = mi2 * 16 + lk * 4 + r;
            float v = acc[mi][ni][r] + bv;
            v = gelu_t(v);
            eb[rowL * 72 + (col ^ (((rowL >> 2) & 3) << 3))] = f2bf(v);
          }
        }
      }
#pragma unroll
      for (int i = 0; i < 8; ++i) {
        int rowL = i * 8 + (lane >> 3);
        int c8 = (lane & 7) * 8;
        bf16x8 yv = *(const bf16x8*)&eb[rowL * 72 + (c8 ^ (((rowL >> 2) & 3) << 3))];
        size_t grow = gr0 + ch * 64 + rowL;
        bf16x8 rv = *(const bf16x8*)(residb + grow * 1024 + gc0 + c8);
        bf16x8 ov;
#pragma unroll
        for (int j = 0; j < 8; ++j)
          ov[j] = (short)f2bf(bf2f((u16)yv[j]) + bf2f((u16)rv[j]));
        *(bf16x8*)(Cout + grow * 2048 + gc0 + c8) = ov;
      }
    }
  }
#undef STAGE_A
#undef STAGE_B
#undef LOAD_A
#undef LOAD_B
#undef MFMA_Q
#undef TILE
#undef BARRIER
#undef ALS
#undef BLS
}

// ---------------- softmax over the 4 bn sim-partials -> ab [B,64] bf16 ----------------
__global__ __launch_bounds__(256) void k_soft(const float* __restrict__ simp,
                                              const float* __restrict__ ssp,
                                              u16* __restrict__ ab) {
  const int wv = threadIdx.x >> 6, lane = threadIdx.x & 63;
  int rowBase = blockIdx.x * 32 + wv * 8;
#pragma unroll
  for (int i = 0; i < 8; ++i) {
    int row = rowBase + i;
    const float* sp = simp + (size_t)row * 128;
    float v = sp[lane] + sp[64 + lane];
    v += __shfl_xor(v, 32);  // every lane: sim[lane & 31] (full over 4 bn)
    float ssv = (lane < 16) ? ssp[(size_t)row * 16 + lane] : 0.f;
    ssv += __shfl_xor(ssv, 1); ssv += __shfl_xor(ssv, 2);
    ssv += __shfl_xor(ssv, 4); ssv += __shfl_xor(ssv, 8);
    float ss = __shfl(ssv, 0);
    float inv = 10.0f / fmaxf(sqrtf(ss), 1e-12f);
    float s = v * inv;
    float m = s;
#pragma unroll
    for (int off = 1; off < 32; off <<= 1) m = fmaxf(m, __shfl_xor(m, off));
    float e = expf(s - m);
    float sum = e;
#pragma unroll
    for (int off = 1; off < 32; off <<= 1) sum += __shfl_xor(sum, off);
    float a = e / sum;
    ab[(size_t)row * 64 + lane] = (lane < 32) ? f2bf(a) : (u16)0;
  }
}

// ---------------- LayerNorm: read y bf16 (low half of each out-row slot), write f32 ----
__global__ __launch_bounds__(256) void k_ln2(u16* __restrict__ ybase,
                                             float* __restrict__ out,
                                             const float* __restrict__ gamma,
                                             const float* __restrict__ beta) {
  __shared__ float sb[8];
  size_t row = blockIdx.x;
  int tid = threadIdx.x;
  ushort4 v4 = ((const ushort4*)(ybase + row * 2048))[tid];
  float y0 = bf2f(v4.x), y1 = bf2f(v4.y), y2 = bf2f(v4.z), y3 = bf2f(v4.w);
  float s = y0 + y1 + y2 + y3;
  float q = y0 * y0 + y1 * y1 + y2 * y2 + y3 * y3;
#pragma unroll
  for (int off = 32; off; off >>= 1) { s += __shfl_xor(s, off); q += __shfl_xor(q, off); }
  if ((tid & 63) == 0) { sb[tid >> 6] = s; sb[4 + (tid >> 6)] = q; }
  __syncthreads();  // also drains all loads before any store below
  s = sb[0] + sb[1] + sb[2] + sb[3];
  q = sb[4] + sb[5] + sb[6] + sb[7];
  float mu = s * (1.f / 1024.f);
  float var = q * (1.f / 1024.f) - mu * mu;
  float rstd = rsqrtf(var + 1e-5f);
  float4 g = ((const float4*)gamma)[tid];
  float4 b = ((const float4*)beta)[tid];
  float4 o;
  o.x = (y0 - mu) * rstd * g.x + b.x;
  o.y = (y1 - mu) * rstd * g.y + b.y;
  o.z = (y2 - mu) * rstd * g.z + b.z;
  o.w = (y3 - mu) * rstd * g.w + b.w;
  ((float4*)(out + (row << 10)))[tid] = o;
}

extern "C" void kernel_launch(void* const* d_in, const int* in_sizes, int n_in,
                              void* d_out, int out_size, void* d_ws, size_t ws_size,
                              hipStream_t stream) {
  const float* x      = (const float*)d_in[0];
  const float* Wi     = (const float*)d_in[1];
  const float* bi     = (const float*)d_in[2];
  const float* Wo     = (const float*)d_in[3];
  const float* bo     = (const float*)d_in[4];
  const float* gamma  = (const float*)d_in[5];
  const float* beta   = (const float*)d_in[6];
  const float* protos = (const float*)d_in[7];
  const int Brows = in_sizes[0] / DD;  // 65536

  u16* xb   = (u16*)d_ws;                        // [B, 1024] bf16
  u16* WiB  = xb + (size_t)Brows * 1024;         // [1024, 1024]
  u16* WoB  = WiB + (size_t)1024 * 1024;         // [1024, 1088]  (Wo1 | P2 | pad)
  u16* pb   = WoB + (size_t)1024 * 1088;         // [32, 1024] normalized
  u16* ab   = pb + (size_t)PP * DD;              // [B, 64] attn (cols 32..63 zero)
  float* simp = (float*)(ab + (size_t)Brows * 64);   // [B, 4, 32] sim partials (per bn)
  float* ssp  = simp + (size_t)Brows * 128;          // [B, 16] ||h||^2 partials (bn*4+wn)
  u16* ybuf = (u16*)d_out;                       // y bf16, u16-stride 2048 (low half of slots)

  k_convert<<<4096, 256, 0, stream>>>(x, xb, Brows * 256);
  k_convert<<<1024, 256, 0, stream>>>(Wi, WiB, 1024 * 1024 / 4);
  k_proto_prep<<<PP, 256, 0, stream>>>(protos, pb);
  k_p2<<<1024, 256, 0, stream>>>(Wo, protos, WoB);

  const int nbn = 1024 / 256;                    // 4 col-blocks
  const int nwg = nbn * (Brows / 256);           // 1024 blocks (mod 8 == 0)

  // h = x @ Wi^T + bi fused with sim/norm partials (h never hits HBM)
  k_gemmF<2, 16><<<nwg, 512, 0, stream>>>(xb, xb, WiB, 1024, bi, nullptr,
                                          nullptr, nbn, pb, simp, ssp);
  // softmax over partials -> attn
  k_soft<<<Brows / 32, 256, 0, stream>>>(simp, ssp, ab);
  // y = bf16(gelu(x @ Wo1^T + attn @ P2 + bo) + bf16(x))  (K = 1088, 17 tiles)
  k_gemmF<1, 17><<<nwg, 512, 0, stream>>>(xb, ab, WoB, 1088, bo, xb,
                                          ybuf, nbn, nullptr, nullptr, nullptr);
  // LayerNorm: y bf16 -> out f32 (in-slot)
  k_ln2<<<Brows, 256, 0, stream>>>(ybuf, (float*)d_out, gamma, beta);
}